// Round 14
// baseline (61.039 us; speedup 1.0000x reference)
//
#include <hip/hip_runtime.h>

// N=8, C=256, H=W=64, A=9, bs=8, F=8, K=64, M=A*N*K=4608
constexpr int N_ = 8, C_ = 256, H_ = 64, W_ = 64, A_ = 9, F_ = 8, K_ = 64;
constexpr int NPOS = 512;                  // N*F*F positions
constexpr int PSTRIDE = 9 * 32;            // per-position partials: [9 anchors][32 slices]
constexpr int NJOBS = A_ * N_ * (C_ / 8);  // 2304 fused jobs (one (a,n), 8 ch each)
#define ALPHA_BS 0.8f                      // ALPHA(0.1) * bs(8)
#define L2E 1.442695040888963f
#define EXPSCL 8388608.0f                  // 2^23
#define EXPBIAS 1065353216.0f              // 127<<23
// minimax quadratic for r(u) = 2^(u-1)/u on u in [1,2):  r ~ Q0 + Q1 u + Q2 u^2
#define Q0 1.436809f
#define Q1 (-0.664625f)
#define Q2 0.223528f

typedef float f32x2 __attribute__((ext_vector_type(2)));

// Corrected Schraudolph exp2, issue-optimized (R12 accuracy: absmax 0.0625,
// all terms approximated). ys = y*2^23 + EXPBIAS, y <= 0. CLAMP FIRST
// (ys>=0 in float, pk-able) so no post-hoc NaN/underflow guard is needed:
// ys==0 -> bits=0 -> e0=+0.0 -> e=0 (graceful underflow).
// Per channel-pair: 1 pk_max + 2 cvt + 2 and_or + 4 fma + 2 mul = 11 insts.
__device__ __forceinline__ f32x2 fastexp2_pair(f32x2 ys) {
    ys.x = fmaxf(ys.x, 0.f);               // pk_max_f32
    ys.y = fmaxf(ys.y, 0.f);
    const int bx = (int)ys.x;              // v_cvt_i32_f32 (trunc)
    const int by = (int)ys.y;
    const float e0x = __int_as_float(bx);  // free
    const float e0y = __int_as_float(by);
    const float ux = __int_as_float((bx & 0x7FFFFF) | 0x3F800000);  // v_and_or_b32
    const float uy = __int_as_float((by & 0x7FFFFF) | 0x3F800000);
    const float qx = fmaf(ux, fmaf(ux, Q2, Q1), Q0);
    const float qy = fmaf(uy, fmaf(uy, Q2, Q1), Q0);
    f32x2 e;
    e.x = e0x * qx;
    e.y = e0y * qy;
    return e;
}

// ---------------------------------------------------------------------------
// kA: conv partials, W register-stationary. 2048 blocks = (pair, g, chunk):
// chunk = bi&7 == XCD id; g = (n,gy); pair picks 2 of 8 gx. Thread t =
// (cl=t>>3, r=t&7) holds W[a][c][r][0..7] in regs (18 float4). Per gx:
// 2 feat float4 loads, 72 FMA, 6-step butterfly -> partials[p][a][chunk*4+wid].
// ---------------------------------------------------------------------------
__global__ __launch_bounds__(256) void kA(const float* __restrict__ feat,
                                          const float* __restrict__ Wreg,
                                          float* __restrict__ partials) {
    const int bi = blockIdx.x;
    const int chunk = bi & 7;
    const int g = (bi >> 3) & 63;
    const int pair = bi >> 9;              // 0..3
    const int n = g >> 3, gy = g & 7;
    const int t = threadIdx.x;
    const int lane = t & 63, wid = t >> 6;
    const int r = t & 7;
    const int c = chunk * 32 + (t >> 3);

    const float* wp = Wreg + chunk * 2048 + t * 8;
    float4 w0[9], w1[9];
#pragma unroll
    for (int a = 0; a < 9; ++a) {
        w0[a] = *(const float4*)(wp + (size_t)a * 16384);
        w1[a] = *(const float4*)(wp + (size_t)a * 16384 + 4);
    }
    const float* frow = feat + (((size_t)n * C_ + c) * H_ + gy * 8 + r) * W_;
#pragma unroll
    for (int i = 0; i < 2; ++i) {
        const int gx = pair * 2 + i;
        const float4 f0 = *(const float4*)(frow + gx * 8);
        const float4 f1 = *(const float4*)(frow + gx * 8 + 4);
        float* pp = partials + (size_t)(g * 8 + gx) * PSTRIDE + chunk * 4 + wid;
#pragma unroll
        for (int a = 0; a < 9; ++a) {
            float s = f0.x * w0[a].x + f0.y * w0[a].y + f0.z * w0[a].z + f0.w * w0[a].w;
            s = fmaf(f1.x, w1[a].x, s);
            s = fmaf(f1.y, w1[a].y, s);
            s = fmaf(f1.z, w1[a].z, s);
            s = fmaf(f1.w, w1[a].w, s);
            s += __shfl_xor(s, 1, 64);     // rows (lane bits 0..2)
            s += __shfl_xor(s, 2, 64);
            s += __shfl_xor(s, 4, 64);
            s += __shfl_xor(s, 8, 64);     // the wave's 8 channels (bits 3..5)
            s += __shfl_xor(s, 16, 64);
            s += __shfl_xor(s, 32, 64);
            if (lane == 0) pp[a * 32] = s;
        }
    }
}

// ---------------------------------------------------------------------------
// kRfB: offsets + bilinear sample + both rois stages (R10 structure).
// R13 established trans+VALU do NOT overlap (hybrid = sum of both), so the
// only lever is fewer issue cycles per exp. Pure Schraudolph, issue-tuned:
// 11 insts/pair vs v_exp's 64-cyc trans occupancy. Inner iter total ~16
// insts (+1 ds_read_b64): predicted ~0.55x of R10's trans version.
// ---------------------------------------------------------------------------
__global__ __launch_bounds__(256, 4) void kRfB(const float* __restrict__ rois_a,
                                               const float* __restrict__ feat,
                                               const float* __restrict__ partials,
                                               const float* __restrict__ breg,
                                               const float* __restrict__ rois_c,
                                               float* __restrict__ out) {
    __shared__ __align__(16) float sa[64][10];
    __shared__ __align__(16) float sb[64][10];
    __shared__ __align__(16) float sc[64][10];
    __shared__ float soff[64];

    const int bi = blockIdx.x;
    const int n  = bi & 7;                 // XCD-aligned image
    const int r9 = bi >> 3;                // 0..287
    const int a9 = r9 >> 5;                // anchor 0..8
    const int cb = (r9 & 31) * 8;          // channel base
    const int na = a9 * N_ + n;
    const int t = threadIdx.x, lane = t & 63, w = t >> 6;
    const int cp = 2 * w;                  // this wave's channel pair
    const size_t base = (size_t)na * 64;

    // ---- offsets: thread (q=t&3, jj=t>>2) reduces 8 of 32 partial slices ----
    {
        const int q = t & 3, jj = t >> 2;
        const float* pp = partials +
            (size_t)((n * 8 + (jj >> 3)) * 8 + (jj & 7)) * PSTRIDE + a9 * 32 + q * 8;
        const float4 v0 = *(const float4*)pp;
        const float4 v1 = *(const float4*)(pp + 4);
        float s = v0.x + v0.y + v0.z + v0.w + v1.x + v1.y + v1.z + v1.w;
        s += __shfl_xor(s, 1, 64);
        s += __shfl_xor(s, 2, 64);
        if (q == 0) soff[jj] = ALPHA_BS * tanhf(s + breg[a9]);
    }

    // ---- stage rois_a / prefetch rois_c (coalesced 32B segments) ----
    float rc[2];
#pragma unroll
    for (int k = 0; k < 2; ++k) {
        int idx = t + 256 * k;
        int i = idx >> 3, cc = idx & 7;
        sa[i][cc] = rois_a[(base + i) * 256 + cb + cc];
        rc[k]     = rois_c[(base + i) * 256 + cb + cc];
    }
    __syncthreads();

    // ---- bilinear sample -> sb: t = (j = t&63, cg = t>>6), 2 channels ----
    {
        const int j = t & 63, cg = t >> 6;
        const int gy = j >> 3, gx = j & 7;
        const float off = soff[j];
        const float cx = 3.5f + 8.0f * gx + off;
        const float cy = 3.5f + 8.0f * gy + off;
        const float x0f = floorf(cx), y0f = floorf(cy);
        const float wx = cx - x0f, wy = cy - y0f;
        const int x0 = (int)x0f, y0 = (int)y0f;    // in [2,60]: clamps never fire
        const float w00 = (1.f - wx) * (1.f - wy), w01 = wx * (1.f - wy);
        const float w10 = (1.f - wx) * wy,         w11 = wx * wy;
#pragma unroll
        for (int k = 0; k < 2; ++k) {
            const int c = cb + cg * 2 + k;
            const float* fp = feat + (((size_t)n * C_ + c) * H_ + y0) * W_ + x0;
            const float v00 = fp[0], v01 = fp[1];
            const float v10 = fp[W_], v11 = fp[W_ + 1];
            sb[j][cg * 2 + k] = w00 * v00 + w01 * v01 + w10 * v10 + w11 * v11;
        }
    }
    __syncthreads();

    // ---- stage 1: a = rois_a (sa), b = sampled (sb) ----
    const f32x2 a1 = *(const f32x2*)&sa[lane][cp];
    const f32x2 b1 = *(const f32x2*)&sb[lane][cp];
    f32x2 o1;
    {
        float mx0 = a1.x, mn0 = a1.x, mx1 = a1.y, mn1 = a1.y;
#pragma unroll
        for (int s = 32; s; s >>= 1) {
            mx0 = fmaxf(mx0, __shfl_xor(mx0, s, 64));
            mn0 = fminf(mn0, __shfl_xor(mn0, s, 64));
            mx1 = fmaxf(mx1, __shfl_xor(mx1, s, 64));
            mn1 = fminf(mn1, __shfl_xor(mn1, s, 64));
        }
        f32x2 m;
        m.x = b1.x > 0.f ? b1.x * mx0 : b1.x * mn0;
        m.y = b1.y > 0.f ? b1.y * mx1 : b1.y * mn1;
        const f32x2 blS = b1 * (L2E * EXPSCL);    // scale folded
        f32x2 mlS;                                // bias folded
        mlS.x = fmaf(-m.x, L2E * EXPSCL, EXPBIAS);
        mlS.y = fmaf(-m.y, L2E * EXPSCL, EXPBIAS);
        f32x2 den = {0.f, 0.f}, num = {0.f, 0.f};
#pragma unroll 8
        for (int i = 0; i < 64; ++i) {
            const f32x2 av = *(const f32x2*)&sa[i][cp];       // uniform -> broadcast
            const f32x2 e = fastexp2_pair(av * blS + mlS);
            den += e;
            num += e * av;
        }
        o1 = b1 + num / den;
    }
    __syncthreads();            // all waves done reading sa/sb

    // re-stage: sa <- o1 (for i-broadcast), sb <- rois_c
    *(f32x2*)&sa[lane][cp] = o1;
#pragma unroll
    for (int k = 0; k < 2; ++k) {
        int idx = t + 256 * k;
        sb[idx >> 3][idx & 7] = rc[k];
    }
    __syncthreads();

    // ---- stage 2: a = o1 (sa), b = rois_c (sb) ----
    {
        const f32x2 b2 = *(const f32x2*)&sb[lane][cp];
        float mx0 = o1.x, mn0 = o1.x, mx1 = o1.y, mn1 = o1.y;
#pragma unroll
        for (int s = 32; s; s >>= 1) {
            mx0 = fmaxf(mx0, __shfl_xor(mx0, s, 64));
            mn0 = fminf(mn0, __shfl_xor(mn0, s, 64));
            mx1 = fmaxf(mx1, __shfl_xor(mx1, s, 64));
            mn1 = fminf(mn1, __shfl_xor(mn1, s, 64));
        }
        f32x2 m;
        m.x = b2.x > 0.f ? b2.x * mx0 : b2.x * mn0;
        m.y = b2.y > 0.f ? b2.y * mx1 : b2.y * mn1;
        const f32x2 blS = b2 * (L2E * EXPSCL);
        f32x2 mlS;
        mlS.x = fmaf(-m.x, L2E * EXPSCL, EXPBIAS);
        mlS.y = fmaf(-m.y, L2E * EXPSCL, EXPBIAS);
        f32x2 den = {0.f, 0.f}, num = {0.f, 0.f};
#pragma unroll 8
        for (int i = 0; i < 64; ++i) {
            const f32x2 av = *(const f32x2*)&sa[i][cp];       // uniform -> broadcast
            const f32x2 e = fastexp2_pair(av * blS + mlS);
            den += e;
            num += e * av;
        }
        *(f32x2*)&sc[lane][cp] = b2 + num / den;
    }
    __syncthreads();

    // ---- coalesced writeback ----
#pragma unroll
    for (int k = 0; k < 2; ++k) {
        int idx = t + 256 * k;
        int i = idx >> 3, cc = idx & 7;
        out[(base + i) * 256 + cb + cc] = sc[i][cc];
    }
}

// ---------------------------------------------------------------------------
extern "C" void kernel_launch(void* const* d_in, const int* in_sizes, int n_in,
                              void* d_out, int out_size, void* d_ws, size_t ws_size,
                              hipStream_t stream) {
    // inputs: ori_feature_shape, rois_feature_a, feature_b, rois_feature_c, W_reg, b_reg
    const float* rois_a = (const float*)d_in[1];
    const float* feat   = (const float*)d_in[2];
    const float* rois_c = (const float*)d_in[3];
    const float* Wreg   = (const float*)d_in[4];
    const float* breg   = (const float*)d_in[5];
    float* out = (float*)d_out;
    float* partials = (float*)d_ws;        // 512*288 floats = 589 KB

    kA<<<dim3(NPOS * 4), dim3(256), 0, stream>>>(feat, Wreg, partials);
    kRfB<<<dim3(NJOBS), dim3(256), 0, stream>>>(rois_a, feat, partials, breg,
                                                rois_c, out);
}

// Round 15
// 47.273 us; speedup vs baseline: 1.2912x; 1.2912x over previous
//
#include <hip/hip_runtime.h>

// N=8, C=256, H=W=64, A=9, bs=8, F=8, K=64, M=A*N*K=4608
constexpr int N_ = 8, C_ = 256, H_ = 64, W_ = 64, A_ = 9, F_ = 8, K_ = 64;
constexpr int NPOS = 512;                  // N*F*F positions
constexpr int PSTRIDE = 9 * 32;            // per-position partials: [9 anchors][32 slices]
constexpr int NJOBS = A_ * N_ * (C_ / 8);  // 2304 fused jobs (one (a,n), 8 ch each)
#define ALPHA_BS 0.8f                      // ALPHA(0.1) * bs(8)
#define L2E 1.442695040888963f

typedef float f32x2 __attribute__((ext_vector_type(2)));

// ---------------------------------------------------------------------------
// kA: conv partials, W register-stationary. 1024 blocks = (quad, g, chunk):
// chunk = bi&7 == XCD id; g = (n,gy); quad picks 4 of 8 gx. 4 blocks/CU
// (no LDS, VGPR ~88). vs R10: half the blocks, 4 gx per W-load -> W L2
// traffic 151 -> 75 MB; feat still read exactly once (33.5 MB HBM floor).
// Thread t = (cl=t>>3, r=t&7) holds W[a][c][r][0..7] in regs (18 float4).
// Per gx: 2 feat float4 loads, 72 FMA, 6-step butterfly -> one scalar per
// (wave, a, gx) -> partials[p][a][chunk*4+wid].
// ---------------------------------------------------------------------------
__global__ __launch_bounds__(256) void kA(const float* __restrict__ feat,
                                          const float* __restrict__ Wreg,
                                          float* __restrict__ partials) {
    const int bi = blockIdx.x;
    const int chunk = bi & 7;
    const int g = (bi >> 3) & 63;
    const int quad = bi >> 9;              // 0..1
    const int n = g >> 3, gy = g & 7;
    const int t = threadIdx.x;
    const int lane = t & 63, wid = t >> 6;
    const int r = t & 7;
    const int c = chunk * 32 + (t >> 3);

    const float* wp = Wreg + chunk * 2048 + t * 8;
    float4 w0[9], w1[9];
#pragma unroll
    for (int a = 0; a < 9; ++a) {
        w0[a] = *(const float4*)(wp + (size_t)a * 16384);
        w1[a] = *(const float4*)(wp + (size_t)a * 16384 + 4);
    }
    const float* frow = feat + (((size_t)n * C_ + c) * H_ + gy * 8 + r) * W_;
#pragma unroll
    for (int i = 0; i < 4; ++i) {
        const int gx = quad * 4 + i;
        const float4 f0 = *(const float4*)(frow + gx * 8);
        const float4 f1 = *(const float4*)(frow + gx * 8 + 4);
        float* pp = partials + (size_t)(g * 8 + gx) * PSTRIDE + chunk * 4 + wid;
#pragma unroll
        for (int a = 0; a < 9; ++a) {
            float s = f0.x * w0[a].x + f0.y * w0[a].y + f0.z * w0[a].z + f0.w * w0[a].w;
            s = fmaf(f1.x, w1[a].x, s);
            s = fmaf(f1.y, w1[a].y, s);
            s = fmaf(f1.z, w1[a].z, s);
            s = fmaf(f1.w, w1[a].w, s);
            s += __shfl_xor(s, 1, 64);     // rows (lane bits 0..2)
            s += __shfl_xor(s, 2, 64);
            s += __shfl_xor(s, 4, 64);
            s += __shfl_xor(s, 8, 64);     // the wave's 8 channels (bits 3..5)
            s += __shfl_xor(s, 16, 64);
            s += __shfl_xor(s, 32, 64);
            if (lane == 0) pp[a * 32] = s;
        }
    }
}

// ---------------------------------------------------------------------------
// kRfB: offsets + bilinear sample + both rois stages — EXACT R10 version
// (trans v_exp_f32). Model (fits R10-R14): v_exp occupies the SIMD ~32cyc/
// wave64, non-overlapping with VALU (R13 hybrid additivity); 2304 exps/lane
// -> 30.7us floor; this kernel measured ~33us = 93% of that roofline.
// ---------------------------------------------------------------------------
__global__ __launch_bounds__(256, 4) void kRfB(const float* __restrict__ rois_a,
                                               const float* __restrict__ feat,
                                               const float* __restrict__ partials,
                                               const float* __restrict__ breg,
                                               const float* __restrict__ rois_c,
                                               float* __restrict__ out) {
    __shared__ __align__(16) float sa[64][10];
    __shared__ __align__(16) float sb[64][10];
    __shared__ __align__(16) float sc[64][10];
    __shared__ float soff[64];

    const int bi = blockIdx.x;
    const int n  = bi & 7;                 // XCD-aligned image
    const int r9 = bi >> 3;                // 0..287
    const int a9 = r9 >> 5;                // anchor 0..8
    const int cb = (r9 & 31) * 8;          // channel base
    const int na = a9 * N_ + n;
    const int t = threadIdx.x, lane = t & 63, w = t >> 6;
    const int cp = 2 * w;                  // this wave's channel pair
    const size_t base = (size_t)na * 64;

    // ---- offsets: thread (q=t&3, jj=t>>2) reduces 8 of 32 partial slices ----
    {
        const int q = t & 3, jj = t >> 2;
        const float* pp = partials +
            (size_t)((n * 8 + (jj >> 3)) * 8 + (jj & 7)) * PSTRIDE + a9 * 32 + q * 8;
        const float4 v0 = *(const float4*)pp;
        const float4 v1 = *(const float4*)(pp + 4);
        float s = v0.x + v0.y + v0.z + v0.w + v1.x + v1.y + v1.z + v1.w;
        s += __shfl_xor(s, 1, 64);
        s += __shfl_xor(s, 2, 64);
        if (q == 0) soff[jj] = ALPHA_BS * tanhf(s + breg[a9]);
    }

    // ---- stage rois_a / prefetch rois_c (coalesced 32B segments) ----
    float rc[2];
#pragma unroll
    for (int k = 0; k < 2; ++k) {
        int idx = t + 256 * k;
        int i = idx >> 3, cc = idx & 7;
        sa[i][cc] = rois_a[(base + i) * 256 + cb + cc];
        rc[k]     = rois_c[(base + i) * 256 + cb + cc];
    }
    __syncthreads();

    // ---- bilinear sample -> sb: t = (j = t&63, cg = t>>6), 2 channels ----
    {
        const int j = t & 63, cg = t >> 6;
        const int gy = j >> 3, gx = j & 7;
        const float off = soff[j];
        const float cx = 3.5f + 8.0f * gx + off;
        const float cy = 3.5f + 8.0f * gy + off;
        const float x0f = floorf(cx), y0f = floorf(cy);
        const float wx = cx - x0f, wy = cy - y0f;
        const int x0 = (int)x0f, y0 = (int)y0f;    // in [2,60]: clamps never fire
        const float w00 = (1.f - wx) * (1.f - wy), w01 = wx * (1.f - wy);
        const float w10 = (1.f - wx) * wy,         w11 = wx * wy;
#pragma unroll
        for (int k = 0; k < 2; ++k) {
            const int c = cb + cg * 2 + k;
            const float* fp = feat + (((size_t)n * C_ + c) * H_ + y0) * W_ + x0;
            const float v00 = fp[0], v01 = fp[1];
            const float v10 = fp[W_], v11 = fp[W_ + 1];
            sb[j][cg * 2 + k] = w00 * v00 + w01 * v01 + w10 * v10 + w11 * v11;
        }
    }
    __syncthreads();

    // ---- stage 1: a = rois_a (sa), b = sampled (sb) ----
    const f32x2 a1 = *(const f32x2*)&sa[lane][cp];
    const f32x2 b1 = *(const f32x2*)&sb[lane][cp];
    f32x2 o1;
    {
        float mx0 = a1.x, mn0 = a1.x, mx1 = a1.y, mn1 = a1.y;
#pragma unroll
        for (int s = 32; s; s >>= 1) {
            mx0 = fmaxf(mx0, __shfl_xor(mx0, s, 64));
            mn0 = fminf(mn0, __shfl_xor(mn0, s, 64));
            mx1 = fmaxf(mx1, __shfl_xor(mx1, s, 64));
            mn1 = fminf(mn1, __shfl_xor(mn1, s, 64));
        }
        f32x2 m;
        m.x = b1.x > 0.f ? b1.x * mx0 : b1.x * mn0;
        m.y = b1.y > 0.f ? b1.y * mx1 : b1.y * mn1;
        const f32x2 bl2 = b1 * L2E;
        const f32x2 ml2 = -m * L2E;
        f32x2 den = {0.f, 0.f}, num = {0.f, 0.f};
#pragma unroll 8
        for (int i = 0; i < 64; ++i) {
            const f32x2 av = *(const f32x2*)&sa[i][cp];   // uniform -> broadcast
            f32x2 eg = av * bl2 + ml2;
            f32x2 e;
            e.x = __builtin_amdgcn_exp2f(eg.x);
            e.y = __builtin_amdgcn_exp2f(eg.y);
            den += e;
            num += e * av;
        }
        o1 = b1 + num / den;
    }
    __syncthreads();            // all waves done reading sa/sb

    // re-stage: sa <- o1 (for i-broadcast), sb <- rois_c
    *(f32x2*)&sa[lane][cp] = o1;
#pragma unroll
    for (int k = 0; k < 2; ++k) {
        int idx = t + 256 * k;
        sb[idx >> 3][idx & 7] = rc[k];
    }
    __syncthreads();

    // ---- stage 2: a = o1 (sa), b = rois_c (sb) ----
    {
        const f32x2 b2 = *(const f32x2*)&sb[lane][cp];
        float mx0 = o1.x, mn0 = o1.x, mx1 = o1.y, mn1 = o1.y;
#pragma unroll
        for (int s = 32; s; s >>= 1) {
            mx0 = fmaxf(mx0, __shfl_xor(mx0, s, 64));
            mn0 = fminf(mn0, __shfl_xor(mn0, s, 64));
            mx1 = fmaxf(mx1, __shfl_xor(mx1, s, 64));
            mn1 = fminf(mn1, __shfl_xor(mn1, s, 64));
        }
        f32x2 m;
        m.x = b2.x > 0.f ? b2.x * mx0 : b2.x * mn0;
        m.y = b2.y > 0.f ? b2.y * mx1 : b2.y * mn1;
        const f32x2 bl2 = b2 * L2E;
        const f32x2 ml2 = -m * L2E;
        f32x2 den = {0.f, 0.f}, num = {0.f, 0.f};
#pragma unroll 8
        for (int i = 0; i < 64; ++i) {
            const f32x2 av = *(const f32x2*)&sa[i][cp];   // uniform -> broadcast
            f32x2 eg = av * bl2 + ml2;
            f32x2 e;
            e.x = __builtin_amdgcn_exp2f(eg.x);
            e.y = __builtin_amdgcn_exp2f(eg.y);
            den += e;
            num += e * av;
        }
        *(f32x2*)&sc[lane][cp] = b2 + num / den;
    }
    __syncthreads();

    // ---- coalesced writeback ----
#pragma unroll
    for (int k = 0; k < 2; ++k) {
        int idx = t + 256 * k;
        int i = idx >> 3, cc = idx & 7;
        out[(base + i) * 256 + cb + cc] = sc[i][cc];
    }
}

// ---------------------------------------------------------------------------
extern "C" void kernel_launch(void* const* d_in, const int* in_sizes, int n_in,
                              void* d_out, int out_size, void* d_ws, size_t ws_size,
                              hipStream_t stream) {
    // inputs: ori_feature_shape, rois_feature_a, feature_b, rois_feature_c, W_reg, b_reg
    const float* rois_a = (const float*)d_in[1];
    const float* feat   = (const float*)d_in[2];
    const float* rois_c = (const float*)d_in[3];
    const float* Wreg   = (const float*)d_in[4];
    const float* breg   = (const float*)d_in[5];
    float* out = (float*)d_out;
    float* partials = (float*)d_ws;        // 512*288 floats = 589 KB

    kA<<<dim3(1024), dim3(256), 0, stream>>>(feat, Wreg, partials);
    kRfB<<<dim3(NJOBS), dim3(256), 0, stream>>>(rois_a, feat, partials, breg,
                                                rois_c, out);
}